// Round 1
// baseline (316.222 us; speedup 1.0000x reference)
//
#include <hip/hip_runtime.h>
#include <hip/hip_fp16.h>

typedef int      v4i __attribute__((ext_vector_type(4)));
typedef int      v2i __attribute__((ext_vector_type(2)));
typedef float    v4f __attribute__((ext_vector_type(4)));
typedef _Float16 v8h __attribute__((ext_vector_type(8)));
typedef _Float16 v4h __attribute__((ext_vector_type(4)));

#define MDIM 8192
#define NDIM 4096
#define KDIM 4096
#define RDIM 64
#define KW   (KDIM / 2)   // int32 words per row of packed data (1 payload byte each)
#define BM 128
#define BN 128
#define BK 128            // int4 elements per K tile
#define BKW (BK / 2)      // 64 int32 words per row per tile
#define LDAB 144          // LDS row stride in bytes (128 + 16 pad)

// Unpack 4 packed words (payload byte in bits[7:0]) -> 8 signed int4 as int8.
// Output k-order within the 8-group is [lo0,lo1,lo2,lo3,hi0,hi1,hi2,hi3] —
// legal because A and B use the identical permutation (dot product invariant).
__device__ __forceinline__ void unpack_w(v4i w, int& lo8, int& hi8) {
    unsigned p01 = __builtin_amdgcn_perm((unsigned)w.y, (unsigned)w.x, 0x0C0C0400u);
    unsigned p23 = __builtin_amdgcn_perm((unsigned)w.w, (unsigned)w.z, 0x0C0C0400u);
    unsigned b4  = __builtin_amdgcn_perm(p23, p01, 0x05040100u);
    unsigned lo = b4 & 0x0F0F0F0Fu;
    unsigned hi = (b4 >> 4) & 0x0F0F0F0Fu;
    // per-byte ((n^8)-8) as two's-complement byte: ((n^8)+120)^128, carry-free
    lo8 = (int)(((lo ^ 0x08080808u) + 0x78787878u) ^ 0x80808080u);
    hi8 = (int)(((hi ^ 0x08080808u) + 0x78787878u) ^ 0x80808080u);
}

__global__ __launch_bounds__(256, 2)
void w4a4_fused(const int* __restrict__ xq, const float* __restrict__ xsc,
                const int* __restrict__ wq, const float* __restrict__ wsc,
                const float* __restrict__ bias, const float* __restrict__ xr,
                const float* __restrict__ wo, float* __restrict__ out)
{
    __shared__ __align__(16) char As[BM * LDAB];
    __shared__ __align__(16) char Bs[BN * LDAB];
    __shared__ float xs_s[BM];
    __shared__ float ws_s[BN];
    __shared__ float bs_s[BN];

    const int tid  = threadIdx.x;
    const int lane = tid & 63;
    const int wid  = tid >> 6;
    const int wm   = wid >> 1;          // wave row (0..1), owns 64 rows
    const int wn   = wid & 1;           // wave col (0..1), owns 64 cols
    const int bx   = blockIdx.x % (NDIM / BN);
    const int by   = blockIdx.x / (NDIM / BN);

    const int srow   = tid >> 4;        // staging row 0..15 (16 rows/pass)
    const int schunk = tid & 15;        // staging chunk: 4 words = 8 int4 elems

    // per-row / per-col scale+bias tiles
    if (tid < BM) {
        xs_s[tid] = xsc[by * BM + tid];
    } else {
        int n = tid - 128;
        ws_s[n] = wsc[bx * BN + n];
        bs_s[n] = bias[bx * BN + n];
    }

    const int* gA = xq + (size_t)(by * BM + srow) * KW + schunk * 4;
    const int* gB = wq + (size_t)(bx * BN + srow) * KW + schunk * 4;
    char* lA = As + srow * LDAB + schunk * 8;
    char* lB = Bs + srow * LDAB + schunk * 8;

    v4i acc[4][4];
#pragma unroll
    for (int i = 0; i < 4; ++i)
#pragma unroll
        for (int j = 0; j < 4; ++j) acc[i][j] = (v4i){0, 0, 0, 0};

    const int lr = lane & 15;            // row/col within a 16-tile
    const int lkb = (lane >> 4) * 16;    // k byte offset within K=64 step (i8)

    for (int kt = 0; kt < KDIM / BK; ++kt) {
        // ---- stage A tile: 128 x 128 int8 (from 128 x 64 packed words) ----
#pragma unroll
        for (int p = 0; p < 8; ++p) {
            v4i w = *(const v4i*)(gA + (size_t)p * 16 * KW + kt * BKW);
            int lo8, hi8;
            unpack_w(w, lo8, hi8);
            *(v2i*)(lA + p * 16 * LDAB) = (v2i){lo8, hi8};
        }
        // ---- stage B tile ----
#pragma unroll
        for (int p = 0; p < 8; ++p) {
            v4i w = *(const v4i*)(gB + (size_t)p * 16 * KW + kt * BKW);
            int lo8, hi8;
            unpack_w(w, lo8, hi8);
            *(v2i*)(lB + p * 16 * LDAB) = (v2i){lo8, hi8};
        }
        __syncthreads();

        // ---- compute: 2 k-steps of mfma_i32_16x16x64_i8 ----
#pragma unroll
        for (int ks = 0; ks < 2; ++ks) {
            v4i av[4], bv[4];
#pragma unroll
            for (int i = 0; i < 4; ++i)
                av[i] = *(const v4i*)(As + (wm * 64 + i * 16 + lr) * LDAB + ks * 64 + lkb);
#pragma unroll
            for (int j = 0; j < 4; ++j)
                bv[j] = *(const v4i*)(Bs + (wn * 64 + j * 16 + lr) * LDAB + ks * 64 + lkb);
#pragma unroll
            for (int i = 0; i < 4; ++i)
#pragma unroll
                for (int j = 0; j < 4; ++j)
                    acc[i][j] = __builtin_amdgcn_mfma_i32_16x16x64_i8(av[i], bv[j], acc[i][j], 0, 0, 0);
        }
        __syncthreads();
    }

    // ================= epilogue: rank-64 outlier GEMM in f16 MFMA ==========
    // LDS is free after the last barrier; reuse As/Bs as f16 tiles [128][72].
    _Float16* Xh = (_Float16*)As;
    _Float16* Wh = (_Float16*)Bs;
#pragma unroll
    for (int p = 0; p < 8; ++p) {
        int row = p * 16 + srow;
        float4 vx = *(const float4*)(xr + (size_t)(by * BM + row) * RDIM + schunk * 4);
        v4h hx = {(_Float16)vx.x, (_Float16)vx.y, (_Float16)vx.z, (_Float16)vx.w};
        *(v4h*)(Xh + row * 72 + schunk * 4) = hx;
        float4 vw = *(const float4*)(wo + (size_t)(bx * BN + row) * RDIM + schunk * 4);
        v4h hw = {(_Float16)vw.x, (_Float16)vw.y, (_Float16)vw.z, (_Float16)vw.w};
        *(v4h*)(Wh + row * 72 + schunk * 4) = hw;
    }
    __syncthreads();

    v4f facc[4][4];
#pragma unroll
    for (int i = 0; i < 4; ++i)
#pragma unroll
        for (int j = 0; j < 4; ++j) facc[i][j] = (v4f){0.f, 0.f, 0.f, 0.f};

    const int lkh = (lane >> 4) * 8;     // k offset within K=32 step (f16)
#pragma unroll
    for (int ks = 0; ks < 2; ++ks) {
        v8h ah[4], bh[4];
#pragma unroll
        for (int i = 0; i < 4; ++i)
            ah[i] = *(const v8h*)(Xh + (wm * 64 + i * 16 + lr) * 72 + ks * 32 + lkh);
#pragma unroll
        for (int j = 0; j < 4; ++j)
            bh[j] = *(const v8h*)(Wh + (wn * 64 + j * 16 + lr) * 72 + ks * 32 + lkh);
#pragma unroll
        for (int i = 0; i < 4; ++i)
#pragma unroll
            for (int j = 0; j < 4; ++j)
                facc[i][j] = __builtin_amdgcn_mfma_f32_16x16x32_f16(ah[i], bh[j], facc[i][j], 0, 0, 0);
    }

    // ---- dequant + bias + outlier, store f32 ----
#pragma unroll
    for (int i = 0; i < 4; ++i) {
        int row0 = wm * 64 + i * 16 + (lane >> 4) * 4;
#pragma unroll
        for (int j = 0; j < 4; ++j) {
            int col = wn * 64 + j * 16 + lr;
            float sw = ws_s[col];
            float bz = bs_s[col];
#pragma unroll
            for (int r = 0; r < 4; ++r) {
                int row = row0 + r;
                float v = (float)acc[i][j][r] * xs_s[row] * sw + bz + facc[i][j][r];
                out[(size_t)(by * BM + row) * NDIM + (bx * BN + col)] = v;
            }
        }
    }
}

extern "C" void kernel_launch(void* const* d_in, const int* in_sizes, int n_in,
                              void* d_out, int out_size, void* d_ws, size_t ws_size,
                              hipStream_t stream) {
    const int*   xq   = (const int*)d_in[0];
    const float* xsc  = (const float*)d_in[1];
    const int*   wq   = (const int*)d_in[2];
    const float* wsc  = (const float*)d_in[3];
    const float* bias = (const float*)d_in[4];
    const float* xr   = (const float*)d_in[5];
    const float* wo   = (const float*)d_in[6];
    float* out = (float*)d_out;

    dim3 grid((MDIM / BM) * (NDIM / BN));   // 64 * 32 = 2048 blocks
    dim3 block(256);
    w4a4_fused<<<grid, block, 0, stream>>>(xq, xsc, wq, wsc, bias, xr, wo, out);
}

// Round 2
// 207.342 us; speedup vs baseline: 1.5251x; 1.5251x over previous
//
#include <hip/hip_runtime.h>
#include <hip/hip_fp16.h>

typedef int      v4i __attribute__((ext_vector_type(4)));
typedef int      v2i __attribute__((ext_vector_type(2)));
typedef float    v4f __attribute__((ext_vector_type(4)));
typedef _Float16 v8h __attribute__((ext_vector_type(8)));
typedef _Float16 v4h __attribute__((ext_vector_type(4)));

#define MDIM 8192
#define NDIM 4096
#define KDIM 4096
#define RDIM 64
#define KW   (KDIM / 2)     // packed int32 words per row
#define BM 128
#define BN 128
#define BK 128              // int8 elements per K tile (2 mfma k-steps)

typedef const __attribute__((address_space(1))) int* gas_ptr;
typedef __attribute__((address_space(3))) int*       las_ptr;

// Unpack 4 packed words (payload byte in bits[7:0]) -> 8 signed int4 as int8.
// k-order within each 8-group is [lo0,lo1,lo2,lo3,hi0,hi1,hi2,hi3]; legal as
// long as A and B use the identical permutation (dot product invariant).
__device__ __forceinline__ void unpack_w(v4i w, int& lo8, int& hi8) {
    unsigned p01 = __builtin_amdgcn_perm((unsigned)w.y, (unsigned)w.x, 0x0C0C0400u);
    unsigned p23 = __builtin_amdgcn_perm((unsigned)w.w, (unsigned)w.z, 0x0C0C0400u);
    unsigned b4  = __builtin_amdgcn_perm(p23, p01, 0x05040100u);
    unsigned lo = b4 & 0x0F0F0F0Fu;
    unsigned hi = (b4 >> 4) & 0x0F0F0F0Fu;
    lo8 = (int)(((lo ^ 0x08080808u) + 0x78787878u) ^ 0x80808080u);
    hi8 = (int)(((hi ^ 0x08080808u) + 0x78787878u) ^ 0x80808080u);
}

// ---------------- kernel 1: repack packed-int32 nibbles -> dense int8 -------
__global__ __launch_bounds__(256)
void repack_int4(const int* __restrict__ xq, const int* __restrict__ wq,
                 char* __restrict__ x8, char* __restrict__ w8)
{
    const size_t XCH = (size_t)MDIM * KW / 4;              // 16B chunks in xq
    const size_t TCH = XCH + (size_t)NDIM * KW / 4;
    size_t stride = (size_t)gridDim.x * blockDim.x;
    for (size_t i = (size_t)blockIdx.x * blockDim.x + threadIdx.x; i < TCH; i += stride) {
        const int* src;
        char* dst;
        if (i < XCH) { src = xq + i * 4;        dst = x8 + i * 8; }
        else { size_t j = i - XCH; src = wq + j * 4; dst = w8 + j * 8; }
        v4i w = *(const v4i*)src;
        int lo8, hi8;
        unpack_w(w, lo8, hi8);
        *(v2i*)dst = (v2i){lo8, hi8};
    }
}

// ---------------- kernel 2: int8 GEMM + dequant + rank-64 outlier ----------
__global__ __launch_bounds__(256, 3)
void w4a4_gemm(const char* __restrict__ x8, const char* __restrict__ w8,
               const float* __restrict__ xsc, const float* __restrict__ wsc,
               const float* __restrict__ bias, const float* __restrict__ xr,
               const float* __restrict__ wo, float* __restrict__ out)
{
    // GEMM phase uses [128][128] int8 linear (global_load_lds requirement);
    // epilogue reuses the same LDS as f16 [128][72] (needs 18432 B).
    __shared__ __align__(16) char As[128 * 144];
    __shared__ __align__(16) char Bs[128 * 144];
    __shared__ float xs_s[BM];
    __shared__ float ws_s[BN];
    __shared__ float bs_s[BN];

    const int tid  = threadIdx.x;
    const int lane = tid & 63;
    const int wid  = tid >> 6;
    const int wm   = wid >> 1;
    const int wn   = wid & 1;

    // bijective XCD swizzle (2048 blocks % 8 == 0)
    const int swz = (blockIdx.x & 7) * 256 + (blockIdx.x >> 3);
    const int bx  = swz & 31;      // N block
    const int by  = swz >> 5;      // M block

    if (tid < BM) {
        xs_s[tid] = xsc[by * BM + tid];
    } else {
        int n = tid - BM;
        ws_s[n] = wsc[bx * BN + n];
        bs_s[n] = bias[bx * BN + n];
    }

    // staging geometry: one wave-issue = 64 lanes x 16B = 1KB = 8 rows of 128B
    const int srow8 = lane >> 3;          // row within 8-row chunk
    const int scol  = (lane & 7) * 16;    // byte col within 128B K-slab
    const char* gA = x8 + (size_t)(by * BM + srow8) * KDIM + scol;
    const char* gB = w8 + (size_t)(bx * BN + srow8) * KDIM + scol;

    v4i acc[4][4];
#pragma unroll
    for (int i = 0; i < 4; ++i)
#pragma unroll
        for (int j = 0; j < 4; ++j) acc[i][j] = (v4i){0, 0, 0, 0};

    const int lr  = lane & 15;
    const int lkb = (lane >> 4) * 16;

    for (int kt = 0; kt < KDIM / BK; ++kt) {
        const size_t kb = (size_t)kt * BK;
#pragma unroll
        for (int q = 0; q < 4; ++q) {
            const int chunk = wid * 4 + q;    // wave-uniform, 0..15
            __builtin_amdgcn_global_load_lds(
                (gas_ptr)(const void*)(gA + (size_t)chunk * 8 * KDIM + kb),
                (las_ptr)(void*)(As + chunk * 1024), 16, 0, 0);
            __builtin_amdgcn_global_load_lds(
                (gas_ptr)(const void*)(gB + (size_t)chunk * 8 * KDIM + kb),
                (las_ptr)(void*)(Bs + chunk * 1024), 16, 0, 0);
        }
        __syncthreads();

#pragma unroll
        for (int ks = 0; ks < 2; ++ks) {
            v4i av[4], bv[4];
#pragma unroll
            for (int i = 0; i < 4; ++i)
                av[i] = *(const v4i*)(As + (wm * 64 + i * 16 + lr) * 128 + ks * 64 + lkb);
#pragma unroll
            for (int j = 0; j < 4; ++j)
                bv[j] = *(const v4i*)(Bs + (wn * 64 + j * 16 + lr) * 128 + ks * 64 + lkb);
#pragma unroll
            for (int i = 0; i < 4; ++i)
#pragma unroll
                for (int j = 0; j < 4; ++j)
                    acc[i][j] = __builtin_amdgcn_mfma_i32_16x16x64_i8(av[i], bv[j], acc[i][j], 0, 0, 0);
        }
        __syncthreads();
    }

    // dequant into the f32 accumulator that the outlier MFMA will extend
    // (C/D fragment layout is dtype-independent on gfx950, so facc can be
    // the C-input of the f16 MFMA; this kills the int acc before the
    // epilogue and halves peak register pressure)
    v4f facc[4][4];
#pragma unroll
    for (int i = 0; i < 4; ++i) {
        const int row0 = wm * 64 + i * 16 + (lane >> 4) * 4;
#pragma unroll
        for (int j = 0; j < 4; ++j) {
            const int col = wn * 64 + j * 16 + lr;
            const float sw = ws_s[col];
            const float bz = bs_s[col];
#pragma unroll
            for (int r = 0; r < 4; ++r)
                facc[i][j][r] = (float)acc[i][j][r] * xs_s[row0 + r] * sw + bz;
        }
    }

    // ---- rank-64 outlier: stage xr/wo as f16 [128][72] into reused LDS ----
    _Float16* Xh = (_Float16*)As;
    _Float16* Wh = (_Float16*)Bs;
    const int srow   = tid >> 4;
    const int schunk = tid & 15;
#pragma unroll
    for (int p = 0; p < 8; ++p) {
        const int row = p * 16 + srow;
        float4 vx = *(const float4*)(xr + (size_t)(by * BM + row) * RDIM + schunk * 4);
        *(v4h*)(Xh + row * 72 + schunk * 4) =
            (v4h){(_Float16)vx.x, (_Float16)vx.y, (_Float16)vx.z, (_Float16)vx.w};
        float4 vw = *(const float4*)(wo + (size_t)(bx * BN + row) * RDIM + schunk * 4);
        *(v4h*)(Wh + row * 72 + schunk * 4) =
            (v4h){(_Float16)vw.x, (_Float16)vw.y, (_Float16)vw.z, (_Float16)vw.w};
    }
    __syncthreads();

    const int lkh = (lane >> 4) * 8;
#pragma unroll
    for (int ks = 0; ks < 2; ++ks) {
        v8h ah[4], bh[4];
#pragma unroll
        for (int i = 0; i < 4; ++i)
            ah[i] = *(const v8h*)(Xh + (wm * 64 + i * 16 + lr) * 72 + ks * 32 + lkh);
#pragma unroll
        for (int j = 0; j < 4; ++j)
            bh[j] = *(const v8h*)(Wh + (wn * 64 + j * 16 + lr) * 72 + ks * 32 + lkh);
#pragma unroll
        for (int i = 0; i < 4; ++i)
#pragma unroll
            for (int j = 0; j < 4; ++j)
                facc[i][j] = __builtin_amdgcn_mfma_f32_16x16x32_f16(ah[i], bh[j], facc[i][j], 0, 0, 0);
    }

    // ---- store ----
#pragma unroll
    for (int i = 0; i < 4; ++i) {
        const int row0 = wm * 64 + i * 16 + (lane >> 4) * 4;
#pragma unroll
        for (int j = 0; j < 4; ++j) {
            const int col = wn * 64 + j * 16 + lr;
#pragma unroll
            for (int r = 0; r < 4; ++r)
                out[(size_t)(by * BM + row0 + r) * NDIM + (bx * BN + col)] = facc[i][j][r];
        }
    }
}

// ---------------- fallback: round-1 fused kernel (if ws too small) ---------
__global__ __launch_bounds__(256, 2)
void w4a4_fused(const int* __restrict__ xq, const float* __restrict__ xsc,
                const int* __restrict__ wq, const float* __restrict__ wsc,
                const float* __restrict__ bias, const float* __restrict__ xr,
                const float* __restrict__ wo, float* __restrict__ out)
{
    __shared__ __align__(16) char As[BM * 144];
    __shared__ __align__(16) char Bs[BN * 144];
    __shared__ float xs_s[BM];
    __shared__ float ws_s[BN];
    __shared__ float bs_s[BN];

    const int tid  = threadIdx.x;
    const int lane = tid & 63;
    const int wid  = tid >> 6;
    const int wm   = wid >> 1;
    const int wn   = wid & 1;
    const int bx   = blockIdx.x % (NDIM / BN);
    const int by   = blockIdx.x / (NDIM / BN);

    const int srow   = tid >> 4;
    const int schunk = tid & 15;

    if (tid < BM) {
        xs_s[tid] = xsc[by * BM + tid];
    } else {
        int n = tid - 128;
        ws_s[n] = wsc[bx * BN + n];
        bs_s[n] = bias[bx * BN + n];
    }

    const int* gA = xq + (size_t)(by * BM + srow) * KW + schunk * 4;
    const int* gB = wq + (size_t)(bx * BN + srow) * KW + schunk * 4;
    char* lA = As + srow * 144 + schunk * 8;
    char* lB = Bs + srow * 144 + schunk * 8;

    v4i acc[4][4];
#pragma unroll
    for (int i = 0; i < 4; ++i)
#pragma unroll
        for (int j = 0; j < 4; ++j) acc[i][j] = (v4i){0, 0, 0, 0};

    const int lr = lane & 15;
    const int lkb = (lane >> 4) * 16;

    for (int kt = 0; kt < KDIM / BK; ++kt) {
#pragma unroll
        for (int p = 0; p < 8; ++p) {
            v4i w = *(const v4i*)(gA + (size_t)p * 16 * KW + kt * (BK / 2));
            int lo8, hi8;
            unpack_w(w, lo8, hi8);
            *(v2i*)(lA + p * 16 * 144) = (v2i){lo8, hi8};
        }
#pragma unroll
        for (int p = 0; p < 8; ++p) {
            v4i w = *(const v4i*)(gB + (size_t)p * 16 * KW + kt * (BK / 2));
            int lo8, hi8;
            unpack_w(w, lo8, hi8);
            *(v2i*)(lB + p * 16 * 144) = (v2i){lo8, hi8};
        }
        __syncthreads();

#pragma unroll
        for (int ks = 0; ks < 2; ++ks) {
            v4i av[4], bv[4];
#pragma unroll
            for (int i = 0; i < 4; ++i)
                av[i] = *(const v4i*)(As + (wm * 64 + i * 16 + lr) * 144 + ks * 64 + lkb);
#pragma unroll
            for (int j = 0; j < 4; ++j)
                bv[j] = *(const v4i*)(Bs + (wn * 64 + j * 16 + lr) * 144 + ks * 64 + lkb);
#pragma unroll
            for (int i = 0; i < 4; ++i)
#pragma unroll
                for (int j = 0; j < 4; ++j)
                    acc[i][j] = __builtin_amdgcn_mfma_i32_16x16x64_i8(av[i], bv[j], acc[i][j], 0, 0, 0);
        }
        __syncthreads();
    }

    _Float16* Xh = (_Float16*)As;
    _Float16* Wh = (_Float16*)Bs;
#pragma unroll
    for (int p = 0; p < 8; ++p) {
        int row = p * 16 + srow;
        float4 vx = *(const float4*)(xr + (size_t)(by * BM + row) * RDIM + schunk * 4);
        *(v4h*)(Xh + row * 72 + schunk * 4) =
            (v4h){(_Float16)vx.x, (_Float16)vx.y, (_Float16)vx.z, (_Float16)vx.w};
        float4 vw = *(const float4*)(wo + (size_t)(bx * BN + row) * RDIM + schunk * 4);
        *(v4h*)(Wh + row * 72 + schunk * 4) =
            (v4h){(_Float16)vw.x, (_Float16)vw.y, (_Float16)vw.z, (_Float16)vw.w};
    }
    __syncthreads();

    v4f facc[4][4];
#pragma unroll
    for (int i = 0; i < 4; ++i)
#pragma unroll
        for (int j = 0; j < 4; ++j) facc[i][j] = (v4f){0.f, 0.f, 0.f, 0.f};

    const int lkh = (lane >> 4) * 8;
#pragma unroll
    for (int ks = 0; ks < 2; ++ks) {
        v8h ah[4], bh[4];
#pragma unroll
        for (int i = 0; i < 4; ++i)
            ah[i] = *(const v8h*)(Xh + (wm * 64 + i * 16 + lr) * 72 + ks * 32 + lkh);
#pragma unroll
        for (int j = 0; j < 4; ++j)
            bh[j] = *(const v8h*)(Wh + (wn * 64 + j * 16 + lr) * 72 + ks * 32 + lkh);
#pragma unroll
        for (int i = 0; i < 4; ++i)
#pragma unroll
            for (int j = 0; j < 4; ++j)
                facc[i][j] = __builtin_amdgcn_mfma_f32_16x16x32_f16(ah[i], bh[j], facc[i][j], 0, 0, 0);
    }

#pragma unroll
    for (int i = 0; i < 4; ++i) {
        int row0 = wm * 64 + i * 16 + (lane >> 4) * 4;
#pragma unroll
        for (int j = 0; j < 4; ++j) {
            int col = wn * 64 + j * 16 + lr;
            float sw = ws_s[col];
            float bz = bs_s[col];
#pragma unroll
            for (int r = 0; r < 4; ++r) {
                int row = row0 + r;
                float v = (float)acc[i][j][r] * xs_s[row] * sw + bz + facc[i][j][r];
                out[(size_t)(by * BM + row) * NDIM + (bx * BN + col)] = v;
            }
        }
    }
}

extern "C" void kernel_launch(void* const* d_in, const int* in_sizes, int n_in,
                              void* d_out, int out_size, void* d_ws, size_t ws_size,
                              hipStream_t stream) {
    const int*   xq   = (const int*)d_in[0];
    const float* xsc  = (const float*)d_in[1];
    const int*   wq   = (const int*)d_in[2];
    const float* wsc  = (const float*)d_in[3];
    const float* bias = (const float*)d_in[4];
    const float* xr   = (const float*)d_in[5];
    const float* wo   = (const float*)d_in[6];
    float* out = (float*)d_out;

    const size_t X8 = (size_t)MDIM * KDIM;   // 32 MiB
    const size_t W8 = (size_t)NDIM * KDIM;   // 16 MiB

    if (ws_size >= X8 + W8) {
        char* x8 = (char*)d_ws;
        char* w8 = x8 + X8;
        repack_int4<<<2048, 256, 0, stream>>>(xq, wq, x8, w8);
        w4a4_gemm<<<(MDIM / BM) * (NDIM / BN), 256, 0, stream>>>(
            x8, w8, xsc, wsc, bias, xr, wo, out);
    } else {
        w4a4_fused<<<(MDIM / BM) * (NDIM / BN), 256, 0, stream>>>(
            xq, xsc, wq, wsc, bias, xr, wo, out);
    }
}

// Round 3
// 172.565 us; speedup vs baseline: 1.8325x; 1.2015x over previous
//
#include <hip/hip_runtime.h>
#include <hip/hip_fp16.h>

typedef int      v4i __attribute__((ext_vector_type(4)));
typedef int      v2i __attribute__((ext_vector_type(2)));
typedef float    v4f __attribute__((ext_vector_type(4)));
typedef _Float16 v8h __attribute__((ext_vector_type(8)));
typedef _Float16 v4h __attribute__((ext_vector_type(4)));

#define MDIM 8192
#define NDIM 4096
#define KDIM 4096
#define RDIM 64
#define KW   (KDIM / 2)
#define NT   (KDIM / 128)        // 32 K-tiles of BK=128 int8

typedef const __attribute__((address_space(1))) char* gas_ptr;
typedef __attribute__((address_space(3))) char*       las_ptr;

// Unpack 4 packed words (payload byte in bits[7:0]) -> 8 signed int4 as int8.
// k-order within each 8-group is [lo0..lo3,hi0..hi3]; legal since A and B use
// the identical permutation.
__device__ __forceinline__ void unpack_w(v4i w, int& lo8, int& hi8) {
    unsigned p01 = __builtin_amdgcn_perm((unsigned)w.y, (unsigned)w.x, 0x0C0C0400u);
    unsigned p23 = __builtin_amdgcn_perm((unsigned)w.w, (unsigned)w.z, 0x0C0C0400u);
    unsigned b4  = __builtin_amdgcn_perm(p23, p01, 0x05040100u);
    unsigned lo = b4 & 0x0F0F0F0Fu;
    unsigned hi = (b4 >> 4) & 0x0F0F0F0Fu;
    lo8 = (int)(((lo ^ 0x08080808u) + 0x78787878u) ^ 0x80808080u);
    hi8 = (int)(((hi ^ 0x08080808u) + 0x78787878u) ^ 0x80808080u);
}

// ---------------- kernel 1: repack packed-int32 nibbles -> dense int8 -------
__global__ __launch_bounds__(256)
void repack_int4(const int* __restrict__ xq, const int* __restrict__ wq,
                 char* __restrict__ x8, char* __restrict__ w8)
{
    const size_t XCH = (size_t)MDIM * KW / 4;
    const size_t TCH = XCH + (size_t)NDIM * KW / 4;
    size_t stride = (size_t)gridDim.x * blockDim.x;
    for (size_t i = (size_t)blockIdx.x * blockDim.x + threadIdx.x; i < TCH; i += stride) {
        const int* src;
        char* dst;
        if (i < XCH) { src = xq + i * 4; dst = x8 + i * 8; }
        else { size_t j = i - XCH; src = wq + j * 4; dst = w8 + j * 8; }
        v4i w = *(const v4i*)src;
        int lo8, hi8;
        unpack_w(w, lo8, hi8);
        *(v2i*)dst = (v2i){lo8, hi8};
    }
}

// ---------------- kernel 2: 256x256 8-phase int8 GEMM + fused epilogue ------
// Issue 2 global_load_lds for one 16KB sub-buffer (256 rows x 64B, rows split
// q=0/1 over 128-row halves; each wave covers 16 rows/issue).
__device__ __forceinline__ void stage2(const char* g, char* l, int kt, int ks) {
    const char* s = g + kt * 128 + ks * 64;
    __builtin_amdgcn_global_load_lds((gas_ptr)(const void*)s,
                                     (las_ptr)(void*)l, 16, 0, 0);
    __builtin_amdgcn_global_load_lds((gas_ptr)(const void*)(s + (size_t)128 * KDIM),
                                     (las_ptr)(void*)(l + 8192), 16, 0, 0);
}

#define VM4 asm volatile("s_waitcnt vmcnt(4)" ::: "memory")
#define NOPW

// Phase: ds-read 8 frags -> stage one sub-buffer -> barrier -> 16 MFMA -> (wait) -> barrier
#define PHASE(PAR, MH, KS, STAGE_STMT, WAIT_STMT) do {                          \
    const char* Ab = &Asub[PAR][KS][0];                                         \
    const char* Bb = &Bsub[PAR][KS][0];                                         \
    v4i a_[4], b_[4];                                                           \
    _Pragma("unroll")                                                           \
    for (int ii = 0; ii < 4; ++ii)                                              \
        a_[ii] = *(const v4i*)(Ab + aoff + ((MH) * 4 + ii) * 1024);             \
    _Pragma("unroll")                                                           \
    for (int jj = 0; jj < 4; ++jj)                                              \
        b_[jj] = *(const v4i*)(Bb + boff + jj * 1024);                          \
    STAGE_STMT;                                                                 \
    __builtin_amdgcn_s_barrier();                                               \
    __builtin_amdgcn_s_setprio(1);                                              \
    _Pragma("unroll")                                                           \
    for (int ii = 0; ii < 4; ++ii)                                              \
        _Pragma("unroll")                                                       \
        for (int jj = 0; jj < 4; ++jj)                                          \
            acc[(MH) * 4 + ii][jj] = __builtin_amdgcn_mfma_i32_16x16x64_i8(     \
                a_[ii], b_[jj], acc[(MH) * 4 + ii][jj], 0, 0, 0);               \
    __builtin_amdgcn_s_setprio(0);                                              \
    WAIT_STMT;                                                                  \
    asm volatile("s_barrier" ::: "memory");                                     \
} while (0)

__global__ __launch_bounds__(512, 2)
void w4a4_gemm8(const char* __restrict__ x8, const char* __restrict__ w8,
                const float* __restrict__ xsc, const float* __restrict__ wsc,
                const float* __restrict__ bias, const float* __restrict__ xr,
                const float* __restrict__ wo, float* __restrict__ out)
{
    // [parity][k-half][256 rows x 64B], swizzled: byte c of row r holds
    // global col c ^ (((r>>1)&3)<<4). 128 KiB total.
    __shared__ __align__(16) char Asub[2][2][16384];
    __shared__ __align__(16) char Bsub[2][2][16384];
    __shared__ float xs_s[256];
    __shared__ float ws_s[256];
    __shared__ float bs_s[256];

    const int tid  = threadIdx.x;
    const int lane = tid & 63;
    const int wid  = tid >> 6;     // 0..7
    const int wm   = wid >> 2;     // M half (0..1)
    const int wn   = wid & 3;      // N quarter (0..3)

    // bijective XCD swizzle: 512 blocks = 8 XCDs x 64
    const int s  = (blockIdx.x & 7) * 64 + (blockIdx.x >> 3);
    const int by = s >> 4;         // 0..31
    const int bx = s & 15;         // 0..15

    if (tid < 256) {
        xs_s[tid] = xsc[by * 256 + tid];
    } else {
        int n = tid - 256;
        ws_s[n] = wsc[bx * 256 + n];
        bs_s[n] = bias[bx * 256 + n];
    }

    // staging geometry: lane covers 16B of row (wid*16 + lane/4), pre-swizzled col
    const int srow = wid * 16 + (lane >> 2);
    const int scol = ((lane & 3) * 16) ^ (((lane >> 3) & 3) << 4);
    const char* gA = x8 + (size_t)(by * 256 + srow) * KDIM + scol;
    const char* gB = w8 + (size_t)(bx * 256 + srow) * KDIM + scol;
    const int ldsW = wid * 1024;

    // fragment read geometry (swizzle XOR is lane-constant)
    const int lr   = lane & 15;
    const int cef  = ((lane >> 4) << 4) ^ (((lr >> 1) & 3) << 4);
    const int aoff = (wm * 128 + lr) * 64 + cef;
    const int boff = (wn * 64  + lr) * 64 + cef;

    v4i acc[8][4];
#pragma unroll
    for (int i = 0; i < 8; ++i)
#pragma unroll
        for (int j = 0; j < 4; ++j) acc[i][j] = (v4i){0, 0, 0, 0};

    // prologue: tiles 0 (both k-halves) and 1 (k-half 0) = 12 issues/wave
    stage2(gA, &Asub[0][0][ldsW], 0, 0);
    stage2(gB, &Bsub[0][0][ldsW], 0, 0);
    stage2(gA, &Asub[0][1][ldsW], 0, 1);
    stage2(gB, &Bsub[0][1][ldsW], 0, 1);
    stage2(gA, &Asub[1][0][ldsW], 1, 0);
    stage2(gB, &Bsub[1][0][ldsW], 1, 0);
    asm volatile("s_waitcnt vmcnt(4)" ::: "memory");
    asm volatile("s_barrier" ::: "memory");

    // 16 iterations x 2 K-tiles. Staged k-tiles clamped at tail (dead slots,
    // uniform vmcnt counts). Ledger: consume distance >= 5 phases; vmcnt(4)
    // at P4/P8 leaves exactly the last 2 sub-buffers in flight.
    for (int it = 0; it < NT / 2; ++it) {
        const int kt1 = 2 * it + 1;
        const int kt2 = (2 * it + 2 < NT) ? 2 * it + 2 : NT - 1;
        const int kt3 = (2 * it + 3 < NT) ? 2 * it + 3 : NT - 1;
        PHASE(0, 0, 0, stage2(gA, &Asub[1][1][ldsW], kt1, 1), NOPW);
        PHASE(0, 1, 0, stage2(gB, &Bsub[1][1][ldsW], kt1, 1), NOPW);
        PHASE(0, 0, 1, stage2(gA, &Asub[0][0][ldsW], kt2, 0), NOPW);
        PHASE(0, 1, 1, stage2(gB, &Bsub[0][0][ldsW], kt2, 0), VM4);
        PHASE(1, 0, 0, stage2(gA, &Asub[0][1][ldsW], kt2, 1), NOPW);
        PHASE(1, 1, 0, stage2(gB, &Bsub[0][1][ldsW], kt2, 1), NOPW);
        PHASE(1, 0, 1, stage2(gA, &Asub[1][0][ldsW], kt3, 0), NOPW);
        PHASE(1, 1, 1, stage2(gB, &Bsub[1][0][ldsW], kt3, 0), VM4);
    }

    // drain DMAs before overwriting LDS with the f16 outlier tiles
    asm volatile("s_waitcnt vmcnt(0)" ::: "memory");
    asm volatile("s_barrier" ::: "memory");

    _Float16* Xh = (_Float16*)&Asub[0][0][0];   // [256][72] f16
    _Float16* Wh = (_Float16*)&Bsub[0][0][0];
    {
        const int rr = tid >> 3;
        const int c8 = (tid & 7) * 8;
#pragma unroll
        for (int p = 0; p < 4; ++p) {
            const int row = p * 64 + rr;
            v4f x0 = *(const v4f*)(xr + (size_t)(by * 256 + row) * RDIM + c8);
            v4f x1 = *(const v4f*)(xr + (size_t)(by * 256 + row) * RDIM + c8 + 4);
            v8h hx = {(_Float16)x0[0], (_Float16)x0[1], (_Float16)x0[2], (_Float16)x0[3],
                      (_Float16)x1[0], (_Float16)x1[1], (_Float16)x1[2], (_Float16)x1[3]};
            *(v8h*)((char*)Xh + (size_t)row * 144 + c8 * 2) = hx;
            v4f w0 = *(const v4f*)(wo + (size_t)(bx * 256 + row) * RDIM + c8);
            v4f w1 = *(const v4f*)(wo + (size_t)(bx * 256 + row) * RDIM + c8 + 4);
            v8h hw = {(_Float16)w0[0], (_Float16)w0[1], (_Float16)w0[2], (_Float16)w0[3],
                      (_Float16)w1[0], (_Float16)w1[1], (_Float16)w1[2], (_Float16)w1[3]};
            *(v8h*)((char*)Wh + (size_t)row * 144 + c8 * 2) = hw;
        }
    }

    // dequant in place (int acc -> f32 bits), overlaps the LDS staging above
#pragma unroll
    for (int i = 0; i < 8; ++i) {
        const int r0 = wm * 128 + i * 16 + ((lane >> 4) << 2);
        const v4f xs4 = *(const v4f*)&xs_s[r0];
#pragma unroll
        for (int j = 0; j < 4; ++j) {
            const int col = wn * 64 + j * 16 + lr;
            const float sw = ws_s[col];
            const float bz = bs_s[col];
            v4f f;
#pragma unroll
            for (int r = 0; r < 4; ++r)
                f[r] = (float)acc[i][j][r] * xs4[r] * sw + bz;
            acc[i][j] = __builtin_bit_cast(v4i, f);
        }
    }
    __syncthreads();

    // rank-64 outlier, f16 MFMA accumulating into the dequantized f32 frags
#pragma unroll
    for (int ks = 0; ks < 2; ++ks) {
        v8h ah[8], bh[4];
#pragma unroll
        for (int i = 0; i < 8; ++i)
            ah[i] = *(const v8h*)((const char*)Xh +
                     (size_t)(wm * 128 + i * 16 + lr) * 144 + ks * 64 + ((lane >> 4) << 4));
#pragma unroll
        for (int j = 0; j < 4; ++j)
            bh[j] = *(const v8h*)((const char*)Wh +
                     (size_t)(wn * 64 + j * 16 + lr) * 144 + ks * 64 + ((lane >> 4) << 4));
#pragma unroll
        for (int i = 0; i < 8; ++i)
#pragma unroll
            for (int j = 0; j < 4; ++j) {
                v4f c = __builtin_bit_cast(v4f, acc[i][j]);
                c = __builtin_amdgcn_mfma_f32_16x16x32_f16(ah[i], bh[j], c, 0, 0, 0);
                acc[i][j] = __builtin_bit_cast(v4i, c);
            }
    }

    const size_t obase = (size_t)(by * 256 + wm * 128 + ((lane >> 4) << 2)) * NDIM
                       + bx * 256 + wn * 64 + lr;
#pragma unroll
    for (int i = 0; i < 8; ++i)
#pragma unroll
        for (int j = 0; j < 4; ++j) {
            v4f f = __builtin_bit_cast(v4f, acc[i][j]);
#pragma unroll
            for (int r = 0; r < 4; ++r)
                out[obase + (size_t)(i * 16 + r) * NDIM + j * 16] = f[r];
        }
}

// ---------------- fallback: fused single-kernel path (ws too small) --------
__global__ __launch_bounds__(256, 2)
void w4a4_fused(const int* __restrict__ xq, const float* __restrict__ xsc,
                const int* __restrict__ wq, const float* __restrict__ wsc,
                const float* __restrict__ bias, const float* __restrict__ xr,
                const float* __restrict__ wo, float* __restrict__ out)
{
    __shared__ __align__(16) char As[128 * 144];
    __shared__ __align__(16) char Bs[128 * 144];
    __shared__ float xs_s[128];
    __shared__ float ws_s[128];
    __shared__ float bs_s[128];

    const int tid  = threadIdx.x;
    const int lane = tid & 63;
    const int wid  = tid >> 6;
    const int wm   = wid >> 1;
    const int wn   = wid & 1;
    const int bx   = blockIdx.x % (NDIM / 128);
    const int by   = blockIdx.x / (NDIM / 128);

    const int srow   = tid >> 4;
    const int schunk = tid & 15;

    if (tid < 128) {
        xs_s[tid] = xsc[by * 128 + tid];
    } else {
        int n = tid - 128;
        ws_s[n] = wsc[bx * 128 + n];
        bs_s[n] = bias[bx * 128 + n];
    }

    const int* gA = xq + (size_t)(by * 128 + srow) * KW + schunk * 4;
    const int* gB = wq + (size_t)(bx * 128 + srow) * KW + schunk * 4;
    char* lA = As + srow * 144 + schunk * 8;
    char* lB = Bs + srow * 144 + schunk * 8;

    v4i acc[4][4];
#pragma unroll
    for (int i = 0; i < 4; ++i)
#pragma unroll
        for (int j = 0; j < 4; ++j) acc[i][j] = (v4i){0, 0, 0, 0};

    const int lr = lane & 15;
    const int lkb = (lane >> 4) * 16;

    for (int kt = 0; kt < KDIM / 128; ++kt) {
#pragma unroll
        for (int p = 0; p < 8; ++p) {
            v4i w = *(const v4i*)(gA + (size_t)p * 16 * KW + kt * 64);
            int lo8, hi8;
            unpack_w(w, lo8, hi8);
            *(v2i*)(lA + p * 16 * 144) = (v2i){lo8, hi8};
        }
#pragma unroll
        for (int p = 0; p < 8; ++p) {
            v4i w = *(const v4i*)(gB + (size_t)p * 16 * KW + kt * 64);
            int lo8, hi8;
            unpack_w(w, lo8, hi8);
            *(v2i*)(lB + p * 16 * 144) = (v2i){lo8, hi8};
        }
        __syncthreads();
#pragma unroll
        for (int ks = 0; ks < 2; ++ks) {
            v4i av[4], bv[4];
#pragma unroll
            for (int i = 0; i < 4; ++i)
                av[i] = *(const v4i*)(As + (wm * 64 + i * 16 + lr) * 144 + ks * 64 + lkb);
#pragma unroll
            for (int j = 0; j < 4; ++j)
                bv[j] = *(const v4i*)(Bs + (wn * 64 + j * 16 + lr) * 144 + ks * 64 + lkb);
#pragma unroll
            for (int i = 0; i < 4; ++i)
#pragma unroll
                for (int j = 0; j < 4; ++j)
                    acc[i][j] = __builtin_amdgcn_mfma_i32_16x16x64_i8(av[i], bv[j], acc[i][j], 0, 0, 0);
        }
        __syncthreads();
    }

    _Float16* Xh = (_Float16*)As;
    _Float16* Wh = (_Float16*)Bs;
#pragma unroll
    for (int p = 0; p < 8; ++p) {
        int row = p * 16 + srow;
        float4 vx = *(const float4*)(xr + (size_t)(by * 128 + row) * RDIM + schunk * 4);
        *(v4h*)(Xh + row * 72 + schunk * 4) =
            (v4h){(_Float16)vx.x, (_Float16)vx.y, (_Float16)vx.z, (_Float16)vx.w};
        float4 vw = *(const float4*)(wo + (size_t)(bx * 128 + row) * RDIM + schunk * 4);
        *(v4h*)(Wh + row * 72 + schunk * 4) =
            (v4h){(_Float16)vw.x, (_Float16)vw.y, (_Float16)vw.z, (_Float16)vw.w};
    }
    __syncthreads();

    v4f facc[4][4];
#pragma unroll
    for (int i = 0; i < 4; ++i)
#pragma unroll
        for (int j = 0; j < 4; ++j) facc[i][j] = (v4f){0.f, 0.f, 0.f, 0.f};

    const int lkh = (lane >> 4) * 8;
#pragma unroll
    for (int ks = 0; ks < 2; ++ks) {
        v8h ah[4], bh[4];
#pragma unroll
        for (int i = 0; i < 4; ++i)
            ah[i] = *(const v8h*)(Xh + (wm * 64 + i * 16 + lr) * 72 + ks * 32 + lkh);
#pragma unroll
        for (int j = 0; j < 4; ++j)
            bh[j] = *(const v8h*)(Wh + (wn * 64 + j * 16 + lr) * 72 + ks * 32 + lkh);
#pragma unroll
        for (int i = 0; i < 4; ++i)
#pragma unroll
            for (int j = 0; j < 4; ++j)
                facc[i][j] = __builtin_amdgcn_mfma_f32_16x16x32_f16(ah[i], bh[j], facc[i][j], 0, 0, 0);
    }

#pragma unroll
    for (int i = 0; i < 4; ++i) {
        int row0 = wm * 64 + i * 16 + (lane >> 4) * 4;
#pragma unroll
        for (int j = 0; j < 4; ++j) {
            int col = wn * 64 + j * 16 + lr;
            float sw = ws_s[col];
            float bz = bs_s[col];
#pragma unroll
            for (int r = 0; r < 4; ++r) {
                int row = row0 + r;
                float v = (float)acc[i][j][r] * xs_s[row] * sw + bz + facc[i][j][r];
                out[(size_t)(by * 128 + row) * NDIM + (bx * 128 + col)] = v;
            }
        }
    }
}

extern "C" void kernel_launch(void* const* d_in, const int* in_sizes, int n_in,
                              void* d_out, int out_size, void* d_ws, size_t ws_size,
                              hipStream_t stream) {
    const int*   xq   = (const int*)d_in[0];
    const float* xsc  = (const float*)d_in[1];
    const int*   wq   = (const int*)d_in[2];
    const float* wsc  = (const float*)d_in[3];
    const float* bias = (const float*)d_in[4];
    const float* xr   = (const float*)d_in[5];
    const float* wo   = (const float*)d_in[6];
    float* out = (float*)d_out;

    const size_t X8 = (size_t)MDIM * KDIM;
    const size_t W8 = (size_t)NDIM * KDIM;

    if (ws_size >= X8 + W8) {
        char* x8 = (char*)d_ws;
        char* w8 = x8 + X8;
        repack_int4<<<2048, 256, 0, stream>>>(xq, wq, x8, w8);
        w4a4_gemm8<<<(MDIM / 256) * (NDIM / 256), 512, 0, stream>>>(
            x8, w8, xsc, wsc, bias, xr, wo, out);
    } else {
        w4a4_fused<<<(MDIM / 128) * (NDIM / 128), 256, 0, stream>>>(
            xq, xsc, wq, wsc, bias, xr, wo, out);
    }
}

// Round 4
// 169.991 us; speedup vs baseline: 1.8602x; 1.0151x over previous
//
#include <hip/hip_runtime.h>
#include <hip/hip_fp16.h>

typedef int      v4i __attribute__((ext_vector_type(4)));
typedef int      v2i __attribute__((ext_vector_type(2)));
typedef float    v4f __attribute__((ext_vector_type(4)));
typedef _Float16 v8h __attribute__((ext_vector_type(8)));
typedef _Float16 v4h __attribute__((ext_vector_type(4)));

#define MDIM 8192
#define NDIM 4096
#define KDIM 4096
#define RDIM 64
#define KW   (KDIM / 2)
#define NT   (KDIM / 128)        // 32 K-tiles of BK=128 int8

typedef const __attribute__((address_space(1))) char* gas_ptr;
typedef __attribute__((address_space(3))) char*       las_ptr;

__device__ __forceinline__ void unpack_w(v4i w, int& lo8, int& hi8) {
    unsigned p01 = __builtin_amdgcn_perm((unsigned)w.y, (unsigned)w.x, 0x0C0C0400u);
    unsigned p23 = __builtin_amdgcn_perm((unsigned)w.w, (unsigned)w.z, 0x0C0C0400u);
    unsigned b4  = __builtin_amdgcn_perm(p23, p01, 0x05040100u);
    unsigned lo = b4 & 0x0F0F0F0Fu;
    unsigned hi = (b4 >> 4) & 0x0F0F0F0Fu;
    lo8 = (int)(((lo ^ 0x08080808u) + 0x78787878u) ^ 0x80808080u);
    hi8 = (int)(((hi ^ 0x08080808u) + 0x78787878u) ^ 0x80808080u);
}

// ---------------- kernel 1: repack packed-int32 nibbles -> dense int8 -------
__global__ __launch_bounds__(256)
void repack_int4(const int* __restrict__ xq, const int* __restrict__ wq,
                 char* __restrict__ x8, char* __restrict__ w8)
{
    const size_t XCH = (size_t)MDIM * KW / 4;
    const size_t TCH = XCH + (size_t)NDIM * KW / 4;
    size_t stride = (size_t)gridDim.x * blockDim.x;
    for (size_t i = (size_t)blockIdx.x * blockDim.x + threadIdx.x; i < TCH; i += stride) {
        const int* src;
        char* dst;
        if (i < XCH) { src = xq + i * 4; dst = x8 + i * 8; }
        else { size_t j = i - XCH; src = wq + j * 4; dst = w8 + j * 8; }
        v4i w = *(const v4i*)src;
        int lo8, hi8;
        unpack_w(w, lo8, hi8);
        *(v2i*)dst = (v2i){lo8, hi8};
    }
}

// ---------------- kernel 2: 256x256 8-phase int8 GEMM, read-ahead pipeline --
__device__ __forceinline__ void stage2(const char* g, char* l, int kt, int ks) {
    const char* s = g + kt * 128 + ks * 64;
    __builtin_amdgcn_global_load_lds((gas_ptr)(const void*)s,
                                     (las_ptr)(void*)l, 16, 0, 0);
    __builtin_amdgcn_global_load_lds((gas_ptr)(const void*)(s + (size_t)128 * KDIM),
                                     (las_ptr)(void*)(l + 8192), 16, 0, 0);
}

#define BAR asm volatile("s_barrier" ::: "memory")
#define VM6 asm volatile("s_waitcnt vmcnt(6)" ::: "memory")
#define VM8 asm volatile("s_waitcnt vmcnt(8)" ::: "memory")

// read the 4 A fragments of M-half MH from sub-buffer [PAR][KS]
#define READ_A(dst, PAR, KS, MH)                                               \
    _Pragma("unroll")                                                          \
    for (int ii = 0; ii < 4; ++ii)                                             \
        dst[ii] = *(const v4i*)((const char*)Asub[PAR][KS] + aoff +            \
                                ((MH) * 4 + ii) * 1024)

#define READ_B(dst, PAR, KS)                                                   \
    _Pragma("unroll")                                                          \
    for (int jj = 0; jj < 4; ++jj)                                             \
        dst[jj] = *(const v4i*)((const char*)Bsub[PAR][KS] + boff + jj * 1024)

#define MMA(AS, BS, MH)                                                        \
    __builtin_amdgcn_s_setprio(1);                                             \
    _Pragma("unroll")                                                          \
    for (int ii = 0; ii < 4; ++ii)                                             \
        _Pragma("unroll")                                                      \
        for (int jj = 0; jj < 4; ++jj)                                         \
            acc[(MH) * 4 + ii][jj] = __builtin_amdgcn_mfma_i32_16x16x64_i8(    \
                AS[ii], BS[jj], acc[(MH) * 4 + ii][jj], 0, 0, 0);              \
    __builtin_amdgcn_s_setprio(0)

__global__ __launch_bounds__(512, 2)
void w4a4_gemm8(const char* __restrict__ x8, const char* __restrict__ w8,
                const float* __restrict__ xsc, const float* __restrict__ wsc,
                const float* __restrict__ bias, const float* __restrict__ xr,
                const float* __restrict__ wo, float* __restrict__ out)
{
    // [parity][k-half][256 rows x 64B], swizzled: byte c of row r holds
    // global col c ^ (((r>>1)&3)<<4). 128 KiB total.
    __shared__ __align__(16) char Asub[2][2][16384];
    __shared__ __align__(16) char Bsub[2][2][16384];
    __shared__ float xs_s[256];
    __shared__ float ws_s[256];
    __shared__ float bs_s[256];

    const int tid  = threadIdx.x;
    const int lane = tid & 63;
    const int wid  = tid >> 6;     // 0..7
    const int wm   = wid >> 2;     // M half (0..1)
    const int wn   = wid & 3;      // N quarter (0..3)

    // bijective XCD swizzle: 512 blocks = 8 XCDs x 64
    const int s  = (blockIdx.x & 7) * 64 + (blockIdx.x >> 3);
    const int by = s >> 4;         // 0..31
    const int bx = s & 15;         // 0..15

    if (tid < 256) {
        xs_s[tid] = xsc[by * 256 + tid];
    } else {
        int n = tid - 256;
        ws_s[n] = wsc[bx * 256 + n];
        bs_s[n] = bias[bx * 256 + n];
    }

    // staging geometry: lane covers 16B of row (wid*16 + lane/4), pre-swizzled col
    const int srow = wid * 16 + (lane >> 2);
    const int scol = ((lane & 3) * 16) ^ (((lane >> 3) & 3) << 4);
    const char* gA = x8 + (size_t)(by * 256 + srow) * KDIM + scol;
    const char* gB = w8 + (size_t)(bx * 256 + srow) * KDIM + scol;
    const int ldsW = wid * 1024;

    // fragment read geometry (swizzle XOR is lane-constant)
    const int lr   = lane & 15;
    const int cef  = ((lane >> 4) << 4) ^ (((lr >> 1) & 3) << 4);
    const int aoff = (wm * 128 + lr) * 64 + cef;
    const int boff = (wn * 64  + lr) * 64 + cef;

    v4i acc[8][4];
#pragma unroll
    for (int i = 0; i < 8; ++i)
#pragma unroll
        for (int j = 0; j < 4; ++j) acc[i][j] = (v4i){0, 0, 0, 0};

    // prologue: stage kt0 (both k-halves) + kt1 (k-half 0); loads 1..12
    stage2(gA, &Asub[0][0][ldsW], 0, 0);   // loads 1-2
    stage2(gB, &Bsub[0][0][ldsW], 0, 0);   // loads 3-4
    stage2(gA, &Asub[0][1][ldsW], 0, 1);   // loads 5-6
    stage2(gB, &Bsub[0][1][ldsW], 0, 1);   // loads 7-8
    stage2(gA, &Asub[1][0][ldsW], 1, 0);   // loads 9-10
    stage2(gB, &Bsub[1][0][ldsW], 1, 0);   // loads 11-12
    VM8;                                   // certify A[0][0], B[0][0]
    BAR;

    // ping-pong fragment sets; read-ahead by exactly one phase.
    v4i a0[4], a1[4], b0[4], b1[4];
    READ_A(a0, 0, 0, 0);
    READ_B(b0, 0, 0);

    // Ledger (per wave, 2 loads/phase): VM6 at odd phases drains exactly the
    // two sub-buffers whose first read-ahead is two phases later. Prologue:
    // P1 drains loads 5-8 (A01,B01 -> read at P2), P3 drains 9-12 (A10,B10
    // -> P4), P5 drains P1,P2 stages (A11,B11 -> P6), P7 drains P3,P4
    // (A00,B00 kt2 -> P8). Steady state identical by induction.
    for (int it = 0; it < NT / 2; ++it) {
        const int kt1 = 2 * it + 1;
        const int kt2 = (2 * it + 2 < NT) ? 2 * it + 2 : NT - 1;
        const int kt3 = (2 * it + 3 < NT) ? 2 * it + 3 : NT - 1;

        // P1: compute (PAR0,KS0,MH0); read A00/MH1 for P2
        READ_A(a1, 0, 0, 1);
        stage2(gA, &Asub[1][1][ldsW], kt1, 1);
        MMA(a0, b0, 0);
        VM6; BAR;
        // P2: compute (PAR0,KS0,MH1); read A01/MH0 + B01 for P3
        READ_A(a0, 0, 1, 0);
        READ_B(b1, 0, 1);
        stage2(gB, &Bsub[1][1][ldsW], kt1, 1);
        MMA(a1, b0, 1);
        BAR;
        // P3: compute (PAR0,KS1,MH0); read A01/MH1 for P4
        READ_A(a1, 0, 1, 1);
        stage2(gA, &Asub[0][0][ldsW], kt2, 0);
        MMA(a0, b1, 0);
        VM6; BAR;
        // P4: compute (PAR0,KS1,MH1); read A10/MH0 + B10 for P5
        READ_A(a0, 1, 0, 0);
        READ_B(b0, 1, 0);
        stage2(gB, &Bsub[0][0][ldsW], kt2, 0);
        MMA(a1, b1, 1);
        BAR;
        // P5: compute (PAR1,KS0,MH0); read A10/MH1 for P6
        READ_A(a1, 1, 0, 1);
        stage2(gA, &Asub[0][1][ldsW], kt2, 1);
        MMA(a0, b0, 0);
        VM6; BAR;
        // P6: compute (PAR1,KS0,MH1); read A11/MH0 + B11 for P7
        READ_A(a0, 1, 1, 0);
        READ_B(b1, 1, 1);
        stage2(gB, &Bsub[0][1][ldsW], kt2, 1);
        MMA(a1, b0, 1);
        BAR;
        // P7: compute (PAR1,KS1,MH0); read A11/MH1 for P8
        READ_A(a1, 1, 1, 1);
        stage2(gA, &Asub[1][0][ldsW], kt3, 0);
        MMA(a0, b1, 0);
        VM6; BAR;
        // P8: compute (PAR1,KS1,MH1); read A00/MH0 + B00 (kt2 data) for next P1
        READ_A(a0, 0, 0, 0);
        READ_B(b0, 0, 0);
        stage2(gB, &Bsub[1][0][ldsW], kt3, 0);
        MMA(a1, b1, 1);
        BAR;
    }

    // drain DMAs before overwriting LDS with the f16 outlier tiles
    asm volatile("s_waitcnt vmcnt(0)" ::: "memory");
    BAR;

    _Float16* Xh = (_Float16*)&Asub[0][0][0];   // [256][72] f16
    _Float16* Wh = (_Float16*)&Bsub[0][0][0];
    {
        const int rr = tid >> 3;
        const int c8 = (tid & 7) * 8;
#pragma unroll
        for (int p = 0; p < 4; ++p) {
            const int row = p * 64 + rr;
            v4f x0 = *(const v4f*)(xr + (size_t)(by * 256 + row) * RDIM + c8);
            v4f x1 = *(const v4f*)(xr + (size_t)(by * 256 + row) * RDIM + c8 + 4);
            v8h hx = {(_Float16)x0[0], (_Float16)x0[1], (_Float16)x0[2], (_Float16)x0[3],
                      (_Float16)x1[0], (_Float16)x1[1], (_Float16)x1[2], (_Float16)x1[3]};
            *(v8h*)((char*)Xh + (size_t)row * 144 + c8 * 2) = hx;
            v4f w0 = *(const v4f*)(wo + (size_t)(bx * 256 + row) * RDIM + c8);
            v4f w1 = *(const v4f*)(wo + (size_t)(bx * 256 + row) * RDIM + c8 + 4);
            v8h hw = {(_Float16)w0[0], (_Float16)w0[1], (_Float16)w0[2], (_Float16)w0[3],
                      (_Float16)w1[0], (_Float16)w1[1], (_Float16)w1[2], (_Float16)w1[3]};
            *(v8h*)((char*)Wh + (size_t)row * 144 + c8 * 2) = hw;
        }
    }

    // dequant in place (int acc -> f32 bits), overlaps the LDS staging above
#pragma unroll
    for (int i = 0; i < 8; ++i) {
        const int r0 = wm * 128 + i * 16 + ((lane >> 4) << 2);
        const v4f xs4 = *(const v4f*)&xs_s[r0];
#pragma unroll
        for (int j = 0; j < 4; ++j) {
            const int col = wn * 64 + j * 16 + lr;
            const float sw = ws_s[col];
            const float bz = bs_s[col];
            v4f f;
#pragma unroll
            for (int r = 0; r < 4; ++r)
                f[r] = (float)acc[i][j][r] * xs4[r] * sw + bz;
            acc[i][j] = __builtin_bit_cast(v4i, f);
        }
    }
    __syncthreads();

    // rank-64 outlier, f16 MFMA accumulating into the dequantized f32 frags
#pragma unroll
    for (int ks = 0; ks < 2; ++ks) {
        v8h ah[8], bh[4];
#pragma unroll
        for (int i = 0; i < 8; ++i)
            ah[i] = *(const v8h*)((const char*)Xh +
                     (size_t)(wm * 128 + i * 16 + lr) * 144 + ks * 64 + ((lane >> 4) << 4));
#pragma unroll
        for (int j = 0; j < 4; ++j)
            bh[j] = *(const v8h*)((const char*)Wh +
                     (size_t)(wn * 64 + j * 16 + lr) * 144 + ks * 64 + ((lane >> 4) << 4));
#pragma unroll
        for (int i = 0; i < 8; ++i)
#pragma unroll
            for (int j = 0; j < 4; ++j) {
                v4f c = __builtin_bit_cast(v4f, acc[i][j]);
                c = __builtin_amdgcn_mfma_f32_16x16x32_f16(ah[i], bh[j], c, 0, 0, 0);
                acc[i][j] = __builtin_bit_cast(v4i, c);
            }
    }

    const size_t obase = (size_t)(by * 256 + wm * 128 + ((lane >> 4) << 2)) * NDIM
                       + bx * 256 + wn * 64 + lr;
#pragma unroll
    for (int i = 0; i < 8; ++i)
#pragma unroll
        for (int j = 0; j < 4; ++j) {
            v4f f = __builtin_bit_cast(v4f, acc[i][j]);
#pragma unroll
            for (int r = 0; r < 4; ++r)
                out[obase + (size_t)(i * 16 + r) * NDIM + j * 16] = f[r];
        }
}

// ---------------- fallback: fused single-kernel path (ws too small) --------
__global__ __launch_bounds__(256, 2)
void w4a4_fused(const int* __restrict__ xq, const float* __restrict__ xsc,
                const int* __restrict__ wq, const float* __restrict__ wsc,
                const float* __restrict__ bias, const float* __restrict__ xr,
                const float* __restrict__ wo, float* __restrict__ out)
{
    __shared__ __align__(16) char As[128 * 144];
    __shared__ __align__(16) char Bs[128 * 144];
    __shared__ float xs_s[128];
    __shared__ float ws_s[128];
    __shared__ float bs_s[128];

    const int tid  = threadIdx.x;
    const int lane = tid & 63;
    const int wid  = tid >> 6;
    const int wm   = wid >> 1;
    const int wn   = wid & 1;
    const int bx   = blockIdx.x % (NDIM / 128);
    const int by   = blockIdx.x / (NDIM / 128);

    const int srow   = tid >> 4;
    const int schunk = tid & 15;

    if (tid < 128) {
        xs_s[tid] = xsc[by * 128 + tid];
    } else {
        int n = tid - 128;
        ws_s[n] = wsc[bx * 128 + n];
        bs_s[n] = bias[bx * 128 + n];
    }

    const int* gA = xq + (size_t)(by * 128 + srow) * KW + schunk * 4;
    const int* gB = wq + (size_t)(bx * 128 + srow) * KW + schunk * 4;
    char* lA = As + srow * 144 + schunk * 8;
    char* lB = Bs + srow * 144 + schunk * 8;

    v4i acc[4][4];
#pragma unroll
    for (int i = 0; i < 4; ++i)
#pragma unroll
        for (int j = 0; j < 4; ++j) acc[i][j] = (v4i){0, 0, 0, 0};

    const int lr = lane & 15;
    const int lkb = (lane >> 4) * 16;

    for (int kt = 0; kt < KDIM / 128; ++kt) {
#pragma unroll
        for (int p = 0; p < 8; ++p) {
            v4i w = *(const v4i*)(gA + (size_t)p * 16 * KW + kt * 64);
            int lo8, hi8;
            unpack_w(w, lo8, hi8);
            *(v2i*)(lA + p * 16 * 144) = (v2i){lo8, hi8};
        }
#pragma unroll
        for (int p = 0; p < 8; ++p) {
            v4i w = *(const v4i*)(gB + (size_t)p * 16 * KW + kt * 64);
            int lo8, hi8;
            unpack_w(w, lo8, hi8);
            *(v2i*)(lB + p * 16 * 144) = (v2i){lo8, hi8};
        }
        __syncthreads();
#pragma unroll
        for (int ks = 0; ks < 2; ++ks) {
            v4i av[4], bv[4];
#pragma unroll
            for (int i = 0; i < 4; ++i)
                av[i] = *(const v4i*)(As + (wm * 64 + i * 16 + lr) * 144 + ks * 64 + lkb);
#pragma unroll
            for (int j = 0; j < 4; ++j)
                bv[j] = *(const v4i*)(Bs + (wn * 64 + j * 16 + lr) * 144 + ks * 64 + lkb);
#pragma unroll
            for (int i = 0; i < 4; ++i)
#pragma unroll
                for (int j = 0; j < 4; ++j)
                    acc[i][j] = __builtin_amdgcn_mfma_i32_16x16x64_i8(av[i], bv[j], acc[i][j], 0, 0, 0);
        }
        __syncthreads();
    }

    _Float16* Xh = (_Float16*)As;
    _Float16* Wh = (_Float16*)Bs;
#pragma unroll
    for (int p = 0; p < 8; ++p) {
        int row = p * 16 + srow;
        float4 vx = *(const float4*)(xr + (size_t)(by * 128 + row) * RDIM + schunk * 4);
        *(v4h*)(Xh + row * 72 + schunk * 4) =
            (v4h){(_Float16)vx.x, (_Float16)vx.y, (_Float16)vx.z, (_Float16)vx.w};
        float4 vw = *(const float4*)(wo + (size_t)(bx * 128 + row) * RDIM + schunk * 4);
        *(v4h*)(Wh + row * 72 + schunk * 4) =
            (v4h){(_Float16)vw.x, (_Float16)vw.y, (_Float16)vw.z, (_Float16)vw.w};
    }
    __syncthreads();

    v4f facc[4][4];
#pragma unroll
    for (int i = 0; i < 4; ++i)
#pragma unroll
        for (int j = 0; j < 4; ++j) facc[i][j] = (v4f){0.f, 0.f, 0.f, 0.f};

    const int lkh = (lane >> 4) * 8;
#pragma unroll
    for (int ks = 0; ks < 2; ++ks) {
        v8h ah[4], bh[4];
#pragma unroll
        for (int i = 0; i < 4; ++i)
            ah[i] = *(const v8h*)(Xh + (wm * 64 + i * 16 + lr) * 72 + ks * 32 + lkh);
#pragma unroll
        for (int j = 0; j < 4; ++j)
            bh[j] = *(const v8h*)(Wh + (wn * 64 + j * 16 + lr) * 72 + ks * 32 + lkh);
#pragma unroll
        for (int i = 0; i < 4; ++i)
#pragma unroll
            for (int j = 0; j < 4; ++j)
                facc[i][j] = __builtin_amdgcn_mfma_f32_16x16x32_f16(ah[i], bh[j], facc[i][j], 0, 0, 0);
    }

#pragma unroll
    for (int i = 0; i < 4; ++i) {
        int row0 = wm * 64 + i * 16 + (lane >> 4) * 4;
#pragma unroll
        for (int j = 0; j < 4; ++j) {
            int col = wn * 64 + j * 16 + lr;
            float sw = ws_s[col];
            float bz = bs_s[col];
#pragma unroll
            for (int r = 0; r < 4; ++r) {
                int row = row0 + r;
                float v = (float)acc[i][j][r] * xs_s[row] * sw + bz + facc[i][j][r];
                out[(size_t)(by * 128 + row) * NDIM + (bx * 128 + col)] = v;
            }
        }
    }
}

extern "C" void kernel_launch(void* const* d_in, const int* in_sizes, int n_in,
                              void* d_out, int out_size, void* d_ws, size_t ws_size,
                              hipStream_t stream) {
    const int*   xq   = (const int*)d_in[0];
    const float* xsc  = (const float*)d_in[1];
    const int*   wq   = (const int*)d_in[2];
    const float* wsc  = (const float*)d_in[3];
    const float* bias = (const float*)d_in[4];
    const float* xr   = (const float*)d_in[5];
    const float* wo   = (const float*)d_in[6];
    float* out = (float*)d_out;

    const size_t X8 = (size_t)MDIM * KDIM;
    const size_t W8 = (size_t)NDIM * KDIM;

    if (ws_size >= X8 + W8) {
        char* x8 = (char*)d_ws;
        char* w8 = x8 + X8;
        repack_int4<<<2048, 256, 0, stream>>>(xq, wq, x8, w8);
        w4a4_gemm8<<<(MDIM / 256) * (NDIM / 256), 512, 0, stream>>>(
            x8, w8, xsc, wsc, bias, xr, wo, out);
    } else {
        w4a4_fused<<<(MDIM / 128) * (NDIM / 128), 256, 0, stream>>>(
            xq, xsc, wq, wsc, bias, xr, wo, out);
    }
}

// Round 5
// 168.382 us; speedup vs baseline: 1.8780x; 1.0096x over previous
//
#include <hip/hip_runtime.h>
#include <hip/hip_fp16.h>

typedef int      v4i __attribute__((ext_vector_type(4)));
typedef int      v2i __attribute__((ext_vector_type(2)));
typedef float    v4f __attribute__((ext_vector_type(4)));
typedef _Float16 v8h __attribute__((ext_vector_type(8)));
typedef _Float16 v4h __attribute__((ext_vector_type(4)));

#define MDIM 8192
#define NDIM 4096
#define KDIM 4096
#define RDIM 64
#define KW   (KDIM / 2)
#define NT   (KDIM / 128)        // 32 K-tiles of BK=128 int8

typedef const __attribute__((address_space(1))) char* gas_ptr;
typedef __attribute__((address_space(3))) char*       las_ptr;

__device__ __forceinline__ void unpack_w(v4i w, int& lo8, int& hi8) {
    unsigned p01 = __builtin_amdgcn_perm((unsigned)w.y, (unsigned)w.x, 0x0C0C0400u);
    unsigned p23 = __builtin_amdgcn_perm((unsigned)w.w, (unsigned)w.z, 0x0C0C0400u);
    unsigned b4  = __builtin_amdgcn_perm(p23, p01, 0x05040100u);
    unsigned lo = b4 & 0x0F0F0F0Fu;
    unsigned hi = (b4 >> 4) & 0x0F0F0F0Fu;
    lo8 = (int)(((lo ^ 0x08080808u) + 0x78787878u) ^ 0x80808080u);
    hi8 = (int)(((hi ^ 0x08080808u) + 0x78787878u) ^ 0x80808080u);
}

// ---------------- kernel 1: repack packed-int32 nibbles -> dense int8 -------
__global__ __launch_bounds__(256)
void repack_int4(const int* __restrict__ xq, const int* __restrict__ wq,
                 char* __restrict__ x8, char* __restrict__ w8)
{
    const size_t XCH = (size_t)MDIM * KW / 4;
    const size_t TCH = XCH + (size_t)NDIM * KW / 4;
    size_t stride = (size_t)gridDim.x * blockDim.x;
    for (size_t i = (size_t)blockIdx.x * blockDim.x + threadIdx.x; i < TCH; i += stride) {
        const int* src;
        char* dst;
        if (i < XCH) { src = xq + i * 4; dst = x8 + i * 8; }
        else { size_t j = i - XCH; src = wq + j * 4; dst = w8 + j * 8; }
        v4i w = *(const v4i*)src;
        int lo8, hi8;
        unpack_w(w, lo8, hi8);
        *(v2i*)dst = (v2i){lo8, hi8};
    }
}

// ---------------- kernel 2: 256x256 merged-4-phase int8 GEMM ----------------
// Per phase: 32 MFMA (full 128x64 wave tile x K=64), 12 ds_read_b128
// (read-AHEAD for next phase), 1 sub-buffer pair staged (4 global_load_lds),
// vmcnt(4), ONE barrier. SGB weave pins {reads,stages} inside the MFMA
// stream. No in-loop setprio (its side-effect edges would pin all ds_reads
// before the MFMA cluster and forbid the weave).
__device__ __forceinline__ void stage2(const char* g, char* l, int kt, int ks) {
    const char* s = g + kt * 128 + ks * 64;
    __builtin_amdgcn_global_load_lds((gas_ptr)(const void*)s,
                                     (las_ptr)(void*)l, 16, 0, 0);
    __builtin_amdgcn_global_load_lds((gas_ptr)(const void*)(s + (size_t)128 * KDIM),
                                     (las_ptr)(void*)(l + 8192), 16, 0, 0);
}

#define BAR asm volatile("s_barrier" ::: "memory")
#define VM4 asm volatile("s_waitcnt vmcnt(4)" ::: "memory")
#define SGB(m, n) __builtin_amdgcn_sched_group_barrier(m, n, 0)

// weave: 12 DS_READ (0x100) + 4 VMEM (0x30) laced through 32 MFMA (0x8)
#define SGBSEQ do {                                                            \
    SGB(0x100, 2); SGB(0x8, 4); SGB(0x100, 2); SGB(0x8, 4);                    \
    SGB(0x100, 2); SGB(0x8, 4); SGB(0x100, 2); SGB(0x8, 4);                    \
    SGB(0x100, 2); SGB(0x8, 4); SGB(0x100, 2); SGB(0x8, 4);                    \
    SGB(0x30, 2);  SGB(0x8, 4); SGB(0x30, 2);  SGB(0x8, 4);                    \
} while (0)

#define READ_A8(dst, PAR, KS)                                                  \
    _Pragma("unroll")                                                          \
    for (int ii = 0; ii < 8; ++ii)                                             \
        dst[ii] = *(const v4i*)((const char*)Asub[PAR][KS] + aoff + ii * 1024)

#define READ_B4(dst, PAR, KS)                                                  \
    _Pragma("unroll")                                                          \
    for (int jj = 0; jj < 4; ++jj)                                             \
        dst[jj] = *(const v4i*)((const char*)Bsub[PAR][KS] + boff + jj * 1024)

#define MMA32(AS, BS)                                                          \
    _Pragma("unroll")                                                          \
    for (int ii = 0; ii < 8; ++ii)                                             \
        _Pragma("unroll")                                                      \
        for (int jj = 0; jj < 4; ++jj)                                         \
            acc[ii][jj] = __builtin_amdgcn_mfma_i32_16x16x64_i8(               \
                AS[ii], BS[jj], acc[ii][jj], 0, 0, 0)

// CUR set computed; NXT set read-ahead from [NPAR][NKS]; stage [SPAR][SKS]<-SKT
#define QPHASE(CA, CB, NA, NB, NPAR, NKS, SPAR, SKS, SKT) do {                 \
    READ_A8(NA, NPAR, NKS);                                                    \
    READ_B4(NB, NPAR, NKS);                                                    \
    stage2(gA, &Asub[SPAR][SKS][ldsW], SKT, SKS);                              \
    stage2(gB, &Bsub[SPAR][SKS][ldsW], SKT, SKS);                              \
    MMA32(CA, CB);                                                             \
    SGBSEQ;                                                                    \
    VM4; BAR;                                                                  \
} while (0)

__global__ __launch_bounds__(512, 2)
void w4a4_gemm8(const char* __restrict__ x8, const char* __restrict__ w8,
                const float* __restrict__ xsc, const float* __restrict__ wsc,
                const float* __restrict__ bias, const float* __restrict__ xr,
                const float* __restrict__ wo, float* __restrict__ out)
{
    // [parity][k-half][256 rows x 64B], swizzled: byte c of row r holds
    // global col c ^ (((r>>1)&3)<<4). 128 KiB total.
    __shared__ __align__(16) char Asub[2][2][16384];
    __shared__ __align__(16) char Bsub[2][2][16384];
    __shared__ float xs_s[256];
    __shared__ float ws_s[256];
    __shared__ float bs_s[256];

    const int tid  = threadIdx.x;
    const int lane = tid & 63;
    const int wid  = tid >> 6;     // 0..7
    const int wm   = wid >> 2;     // M half (0..1)
    const int wn   = wid & 3;      // N quarter (0..3)

    // bijective XCD swizzle: 512 blocks = 8 XCDs x 64
    const int s  = (blockIdx.x & 7) * 64 + (blockIdx.x >> 3);
    const int by = s >> 4;         // 0..31
    const int bxn = s & 15;        // 0..15

    if (tid < 256) {
        xs_s[tid] = xsc[by * 256 + tid];
    } else {
        int n = tid - 256;
        ws_s[n] = wsc[bxn * 256 + n];
        bs_s[n] = bias[bxn * 256 + n];
    }

    // staging geometry: lane covers 16B of row (wid*16 + lane/4), pre-swizzled col
    const int srow = wid * 16 + (lane >> 2);
    const int scol = ((lane & 3) * 16) ^ (((lane >> 3) & 3) << 4);
    const char* gA = x8 + (size_t)(by * 256 + srow) * KDIM + scol;
    const char* gB = w8 + (size_t)(bxn * 256 + srow) * KDIM + scol;
    const int ldsW = wid * 1024;

    // fragment read geometry (swizzle XOR is lane-constant)
    const int lr   = lane & 15;
    const int cef  = ((lane >> 4) << 4) ^ (((lr >> 1) & 3) << 4);
    const int aoff = (wm * 128 + lr) * 64 + cef;
    const int boff = (wn * 64  + lr) * 64 + cef;

    v4i acc[8][4];
#pragma unroll
    for (int i = 0; i < 8; ++i)
#pragma unroll
        for (int j = 0; j < 4; ++j) acc[i][j] = (v4i){0, 0, 0, 0};

    // prologue: stage [0][0]@kt0, [0][1]@kt0, [1][0]@kt1 (12 loads/wave)
    stage2(gA, &Asub[0][0][ldsW], 0, 0);   // loads 1-2
    stage2(gB, &Bsub[0][0][ldsW], 0, 0);   // loads 3-4
    stage2(gA, &Asub[0][1][ldsW], 0, 1);   // loads 5-6
    stage2(gB, &Bsub[0][1][ldsW], 0, 1);   // loads 7-8
    stage2(gA, &Asub[1][0][ldsW], 1, 0);   // loads 9-10
    stage2(gB, &Bsub[1][0][ldsW], 1, 0);   // loads 11-12
    VM4;                                   // certify [0][0] + [0][1]
    BAR;

    // ping-pong fragment sets; read-ahead by exactly one phase
    v4i fa0[8], fb0[4], fa1[8], fb1[4];
    READ_A8(fa0, 0, 0);
    READ_B4(fb0, 0, 0);

    // Ledger (4 loads/phase/wave): stage at Qi is ds_read at Qi+2; VM4 at
    // every phase end certifies through the loads staged 2 phases earlier.
    // Q1-end: drains to Q1's 4 -> certifies prologue [1][0] (read at Q2).
    // Steady state identical by induction. WAR: every stage targets a slot
    // whose last reads completed >=1 phase earlier (lgkm-before-MFMA + BAR).
    for (int it = 0; it < NT / 2; ++it) {
        const int kt1 = 2 * it + 1;
        const int kt2 = (2 * it + 2 < NT) ? 2 * it + 2 : NT - 1;
        const int kt3 = (2 * it + 3 < NT) ? 2 * it + 3 : NT - 1;
        // Q1: compute [0][0]; read [0][1]; stage [1][1]@kt1
        QPHASE(fa0, fb0, fa1, fb1, 0, 1, 1, 1, kt1);
        // Q2: compute [0][1]; read [1][0]; stage [0][0]@kt2
        QPHASE(fa1, fb1, fa0, fb0, 1, 0, 0, 0, kt2);
        // Q3: compute [1][0]; read [1][1]; stage [0][1]@kt2
        QPHASE(fa0, fb0, fa1, fb1, 1, 1, 0, 1, kt2);
        // Q4: compute [1][1]; read [0][0](next kt); stage [1][0]@kt3
        QPHASE(fa1, fb1, fa0, fb0, 0, 0, 1, 0, kt3);
    }

    // drain DMAs before overwriting LDS with the f16 outlier tiles
    asm volatile("s_waitcnt vmcnt(0)" ::: "memory");
    BAR;

    _Float16* Xh = (_Float16*)&Asub[0][0][0];   // [256][72] f16
    _Float16* Wh = (_Float16*)&Bsub[0][0][0];
    {
        const int rr = tid >> 3;
        const int c8 = (tid & 7) * 8;
#pragma unroll
        for (int p = 0; p < 4; ++p) {
            const int row = p * 64 + rr;
            v4f x0 = *(const v4f*)(xr + (size_t)(by * 256 + row) * RDIM + c8);
            v4f x1 = *(const v4f*)(xr + (size_t)(by * 256 + row) * RDIM + c8 + 4);
            v8h hx = {(_Float16)x0[0], (_Float16)x0[1], (_Float16)x0[2], (_Float16)x0[3],
                      (_Float16)x1[0], (_Float16)x1[1], (_Float16)x1[2], (_Float16)x1[3]};
            *(v8h*)((char*)Xh + (size_t)row * 144 + c8 * 2) = hx;
            v4f w0 = *(const v4f*)(wo + (size_t)(bxn * 256 + row) * RDIM + c8);
            v4f w1 = *(const v4f*)(wo + (size_t)(bxn * 256 + row) * RDIM + c8 + 4);
            v8h hw = {(_Float16)w0[0], (_Float16)w0[1], (_Float16)w0[2], (_Float16)w0[3],
                      (_Float16)w1[0], (_Float16)w1[1], (_Float16)w1[2], (_Float16)w1[3]};
            *(v8h*)((char*)Wh + (size_t)row * 144 + c8 * 2) = hw;
        }
    }

    // dequant in place (int acc -> f32 bits), overlaps the LDS staging above
#pragma unroll
    for (int i = 0; i < 8; ++i) {
        const int r0 = wm * 128 + i * 16 + ((lane >> 4) << 2);
        const v4f xs4 = *(const v4f*)&xs_s[r0];
#pragma unroll
        for (int j = 0; j < 4; ++j) {
            const int col = wn * 64 + j * 16 + lr;
            const float sw = ws_s[col];
            const float bz = bs_s[col];
            v4f f;
#pragma unroll
            for (int r = 0; r < 4; ++r)
                f[r] = (float)acc[i][j][r] * xs4[r] * sw + bz;
            acc[i][j] = __builtin_bit_cast(v4i, f);
        }
    }
    __syncthreads();

    // rank-64 outlier, f16 MFMA accumulating into the dequantized f32 frags
#pragma unroll
    for (int ks = 0; ks < 2; ++ks) {
        v8h ah[8], bh[4];
#pragma unroll
        for (int i = 0; i < 8; ++i)
            ah[i] = *(const v8h*)((const char*)Xh +
                     (size_t)(wm * 128 + i * 16 + lr) * 144 + ks * 64 + ((lane >> 4) << 4));
#pragma unroll
        for (int j = 0; j < 4; ++j)
            bh[j] = *(const v8h*)((const char*)Wh +
                     (size_t)(wn * 64 + j * 16 + lr) * 144 + ks * 64 + ((lane >> 4) << 4));
#pragma unroll
        for (int i = 0; i < 8; ++i)
#pragma unroll
            for (int j = 0; j < 4; ++j) {
                v4f c = __builtin_bit_cast(v4f, acc[i][j]);
                c = __builtin_amdgcn_mfma_f32_16x16x32_f16(ah[i], bh[j], c, 0, 0, 0);
                acc[i][j] = __builtin_bit_cast(v4i, c);
            }
    }

    const size_t obase = (size_t)(by * 256 + wm * 128 + ((lane >> 4) << 2)) * NDIM
                       + bxn * 256 + wn * 64 + lr;
#pragma unroll
    for (int i = 0; i < 8; ++i)
#pragma unroll
        for (int j = 0; j < 4; ++j) {
            v4f f = __builtin_bit_cast(v4f, acc[i][j]);
#pragma unroll
            for (int r = 0; r < 4; ++r)
                out[obase + (size_t)(i * 16 + r) * NDIM + j * 16] = f[r];
        }
}

// ---------------- fallback: fused single-kernel path (ws too small) --------
__global__ __launch_bounds__(256, 2)
void w4a4_fused(const int* __restrict__ xq, const float* __restrict__ xsc,
                const int* __restrict__ wq, const float* __restrict__ wsc,
                const float* __restrict__ bias, const float* __restrict__ xr,
                const float* __restrict__ wo, float* __restrict__ out)
{
    __shared__ __align__(16) char As[128 * 144];
    __shared__ __align__(16) char Bs[128 * 144];
    __shared__ float xs_s[128];
    __shared__ float ws_s[128];
    __shared__ float bs_s[128];

    const int tid  = threadIdx.x;
    const int lane = tid & 63;
    const int wid  = tid >> 6;
    const int wm   = wid >> 1;
    const int wn   = wid & 1;
    const int bx   = blockIdx.x % (NDIM / 128);
    const int by   = blockIdx.x / (NDIM / 128);

    const int srow   = tid >> 4;
    const int schunk = tid & 15;

    if (tid < 128) {
        xs_s[tid] = xsc[by * 128 + tid];
    } else {
        int n = tid - 128;
        ws_s[n] = wsc[bx * 128 + n];
        bs_s[n] = bias[bx * 128 + n];
    }

    const int* gA = xq + (size_t)(by * 128 + srow) * KW + schunk * 4;
    const int* gB = wq + (size_t)(bx * 128 + srow) * KW + schunk * 4;
    char* lA = As + srow * 144 + schunk * 8;
    char* lB = Bs + srow * 144 + schunk * 8;

    v4i acc[4][4];
#pragma unroll
    for (int i = 0; i < 4; ++i)
#pragma unroll
        for (int j = 0; j < 4; ++j) acc[i][j] = (v4i){0, 0, 0, 0};

    const int lr = lane & 15;
    const int lkb = (lane >> 4) * 16;

    for (int kt = 0; kt < KDIM / 128; ++kt) {
#pragma unroll
        for (int p = 0; p < 8; ++p) {
            v4i w = *(const v4i*)(gA + (size_t)p * 16 * KW + kt * 64);
            int lo8, hi8;
            unpack_w(w, lo8, hi8);
            *(v2i*)(lA + p * 16 * 144) = (v2i){lo8, hi8};
        }
#pragma unroll
        for (int p = 0; p < 8; ++p) {
            v4i w = *(const v4i*)(gB + (size_t)p * 16 * KW + kt * 64);
            int lo8, hi8;
            unpack_w(w, lo8, hi8);
            *(v2i*)(lB + p * 16 * 144) = (v2i){lo8, hi8};
        }
        __syncthreads();
#pragma unroll
        for (int ks = 0; ks < 2; ++ks) {
            v4i av[4], bv[4];
#pragma unroll
            for (int i = 0; i < 4; ++i)
                av[i] = *(const v4i*)(As + (wm * 64 + i * 16 + lr) * 144 + ks * 64 + lkb);
#pragma unroll
            for (int j = 0; j < 4; ++j)
                bv[j] = *(const v4i*)(Bs + (wn * 64 + j * 16 + lr) * 144 + ks * 64 + lkb);
#pragma unroll
            for (int i = 0; i < 4; ++i)
#pragma unroll
                for (int j = 0; j < 4; ++j)
                    acc[i][j] = __builtin_amdgcn_mfma_i32_16x16x64_i8(av[i], bv[j], acc[i][j], 0, 0, 0);
        }
        __syncthreads();
    }

    _Float16* Xh = (_Float16*)As;
    _Float16* Wh = (_Float16*)Bs;
#pragma unroll
    for (int p = 0; p < 8; ++p) {
        int row = p * 16 + srow;
        float4 vx = *(const float4*)(xr + (size_t)(by * 128 + row) * RDIM + schunk * 4);
        *(v4h*)(Xh + row * 72 + schunk * 4) =
            (v4h){(_Float16)vx.x, (_Float16)vx.y, (_Float16)vx.z, (_Float16)vx.w};
        float4 vw = *(const float4*)(wo + (size_t)(bx * 128 + row) * RDIM + schunk * 4);
        *(v4h*)(Wh + row * 72 + schunk * 4) =
            (v4h){(_Float16)vw.x, (_Float16)vw.y, (_Float16)vw.z, (_Float16)vw.w};
    }
    __syncthreads();

    v4f facc[4][4];
#pragma unroll
    for (int i = 0; i < 4; ++i)
#pragma unroll
        for (int j = 0; j < 4; ++j) facc[i][j] = (v4f){0.f, 0.f, 0.f, 0.f};

    const int lkh = (lane >> 4) * 8;
#pragma unroll
    for (int ks = 0; ks < 2; ++ks) {
        v8h ah[4], bh[4];
#pragma unroll
        for (int i = 0; i < 4; ++i)
            ah[i] = *(const v8h*)(Xh + (wm * 64 + i * 16 + lr) * 72 + ks * 32 + lkh);
#pragma unroll
        for (int j = 0; j < 4; ++j)
            bh[j] = *(const v8h*)(Wh + (wn * 64 + j * 16 + lr) * 72 + ks * 32 + lkh);
#pragma unroll
        for (int i = 0; i < 4; ++i)
#pragma unroll
            for (int j = 0; j < 4; ++j)
                facc[i][j] = __builtin_amdgcn_mfma_f32_16x16x32_f16(ah[i], bh[j], facc[i][j], 0, 0, 0);
    }

#pragma unroll
    for (int i = 0; i < 4; ++i) {
        int row0 = wm * 64 + i * 16 + (lane >> 4) * 4;
#pragma unroll
        for (int j = 0; j < 4; ++j) {
            int col = wn * 64 + j * 16 + lr;
            float sw = ws_s[col];
            float bz = bs_s[col];
#pragma unroll
            for (int r = 0; r < 4; ++r) {
                int row = row0 + r;
                float v = (float)acc[i][j][r] * xs_s[row] * sw + bz + facc[i][j][r];
                out[(size_t)(by * 128 + row) * NDIM + (bx * 128 + col)] = v;
            }
        }
    }
}

extern "C" void kernel_launch(void* const* d_in, const int* in_sizes, int n_in,
                              void* d_out, int out_size, void* d_ws, size_t ws_size,
                              hipStream_t stream) {
    const int*   xq   = (const int*)d_in[0];
    const float* xsc  = (const float*)d_in[1];
    const int*   wq   = (const int*)d_in[2];
    const float* wsc  = (const float*)d_in[3];
    const float* bias = (const float*)d_in[4];
    const float* xr   = (const float*)d_in[5];
    const float* wo   = (const float*)d_in[6];
    float* out = (float*)d_out;

    const size_t X8 = (size_t)MDIM * KDIM;
    const size_t W8 = (size_t)NDIM * KDIM;

    if (ws_size >= X8 + W8) {
        char* x8 = (char*)d_ws;
        char* w8 = x8 + X8;
        repack_int4<<<2048, 256, 0, stream>>>(xq, wq, x8, w8);
        w4a4_gemm8<<<(MDIM / 256) * (NDIM / 256), 512, 0, stream>>>(
            x8, w8, xsc, wsc, bias, xr, wo, out);
    } else {
        w4a4_fused<<<(MDIM / 128) * (NDIM / 128), 256, 0, stream>>>(
            xq, xsc, wq, wsc, bias, xr, wo, out);
    }
}